// Round 5
// baseline (1154.507 us; speedup 1.0000x reference)
//
#include <hip/hip_runtime.h>
#include <hip/hip_cooperative_groups.h>
#include <hip/hip_bf16.h>

namespace cg = cooperative_groups;

typedef __attribute__((ext_vector_type(8))) __bf16 bf16x8;
typedef __attribute__((ext_vector_type(4))) float f32x4;

#define AVG_DEG_LOG 2.833213344056216f

__device__ __forceinline__ unsigned short f2bf(float f) {
  union { float f; unsigned int u; } a; a.f = f;
  unsigned int r = a.u + 0x7FFFu + ((a.u >> 16) & 1u);
  return (unsigned short)(r >> 16);
}

__device__ __forceinline__ uint2 pack4(f32x4 a) {
  uint2 u;
  u.x = (unsigned)f2bf(a[0]) | ((unsigned)f2bf(a[1]) << 16);
  u.y = (unsigned)f2bf(a[2]) | ((unsigned)f2bf(a[3]) << 16);
  return u;
}

// ---------------- cooperative prep + aggregation ----------------
// Phases (grid.sync between): A hist+wconv, B distributed scan, C scatter, D agg.
// No GEMM here: keeping the MFMA accumulators out avoids the R2 spill disaster.
__global__ __launch_bounds__(256) void prep_agg_kernel(
    const float* __restrict__ x, const int* __restrict__ index,
    const float* __restrict__ W,
    int E, int Nn,
    int* __restrict__ cnt, int* __restrict__ cursor, int* __restrict__ offsets,
    int* __restrict__ bsums, int* __restrict__ edge_ids,
    unsigned short* __restrict__ agg4, float* __restrict__ amp, float* __restrict__ att,
    unsigned short* __restrict__ Wb) {
  cg::grid_group grid = cg::this_grid();
  __shared__ int wsumS[4];
  __shared__ int tS[256];

  const int t = threadIdx.x;
  const int lane = t & 63;
  const int warp = t >> 6;
  const int G = gridDim.x;
  const int T = G << 8;
  const int tid = blockIdx.x * 256 + t;

  // ---------------- Phase A: wconv + hist ----------------
  const int n4 = 128 * 1536 / 4;
  for (int i = tid; i < n4; i += T) {
    float4 v = ((const float4*)W)[i];
    ushort4 o;
    o.x = f2bf(v.x); o.y = f2bf(v.y); o.z = f2bf(v.z); o.w = f2bf(v.w);
    ((ushort4*)Wb)[i] = o;
  }
  for (int i = tid; i < E; i += T) atomicAdd(&cnt[index[i]], 1);

  __threadfence();
  grid.sync();

  // ---------------- Phase B: exclusive scan (T >= 65536 >= Nn+1) ----------------
  int myv = (tid < Nn) ? cnt[tid] : 0;
  int incl = myv;
#pragma unroll
  for (int d = 1; d < 64; d <<= 1) {
    int u = __shfl_up(incl, d, 64);
    if (lane >= d) incl += u;
  }
  if (lane == 63) wsumS[warp] = incl;
  __syncthreads();
  int wpre = 0;
#pragma unroll
  for (int w = 0; w < 4; ++w) {
    int s = wsumS[w];
    if (w < warp) wpre += s;
  }
  if (t == 0) bsums[blockIdx.x] = wsumS[0] + wsumS[1] + wsumS[2] + wsumS[3];
  __threadfence();
  grid.sync();
  if (blockIdx.x == 0) {
    int K = (G + 255) >> 8;  // <= 8 (G capped at 2048)
    int base = t * K;
    int vals[8];
    int s = 0;
    for (int k = 0; k < K; ++k) {
      int id = base + k;
      int v = (id < G) ? bsums[id] : 0;
      vals[k] = s;  // local exclusive prefix
      s += v;
    }
    tS[t] = s;
    __syncthreads();
    int val = s;
    for (int off = 1; off < 256; off <<= 1) {
      int add = (t >= off) ? tS[t - off] : 0;
      __syncthreads();
      val += add;
      tS[t] = val;
      __syncthreads();
    }
    int excl = val - s;
    for (int k = 0; k < K; ++k) {
      int id = base + k;
      if (id < G) bsums[id] = excl + vals[k];
    }
  }
  __threadfence();
  grid.sync();
  int pre = bsums[blockIdx.x] + wpre + (incl - myv);
  if (tid < Nn) offsets[tid] = pre;
  if (tid == 0) offsets[Nn] = E;  // all edges land in [0,Nn)

  __threadfence();
  grid.sync();

  // ---------------- Phase C: scatter ----------------
  for (int i = tid; i < E; i += T) {
    int n = index[i];
    int p = atomicAdd(&cursor[n], 1);
    edge_ids[offsets[n] + p] = i;
  }

  __threadfence();
  grid.sync();

  // ---------------- Phase D: aggregation (one wave per node, grid-stride) ----------------
  {
    const int nwaves = T >> 6;
    const int gw = tid >> 6;
    const int half = lane >> 5;
    const int fh = (lane & 31) * 4;
    const float* xb = x + fh;
    for (int wid = gw; wid < Nn; wid += nwaves) {
      int offs = offsets[wid];
      int deg = offsets[wid + 1] - offs;
      f32x4 s = {0.f, 0.f, 0.f, 0.f}, q = {0.f, 0.f, 0.f, 0.f};
      f32x4 mn = {INFINITY, INFINITY, INFINITY, INFINITY};
      f32x4 mx = {-INFINITY, -INFINITY, -INFINITY, -INFINITY};
      for (int i = 0; i < deg; i += 64) {
        int myid = 0;
        if (i + lane < deg) myid = edge_ids[offs + i + lane];
        int c = deg - i; if (c > 64) c = 64;
        for (int ii = 0; ii < c; ii += 16) {
          int e[8];
          bool val[8];
#pragma unroll
          for (int k = 0; k < 8; ++k) {
            int p = ii + 2 * k + half;
            val[k] = p < c;
            int pc = val[k] ? p : c - 1;
            e[k] = __shfl(myid, pc, 64);
          }
          f32x4 v[8];
#pragma unroll
          for (int k = 0; k < 8; ++k)
            v[k] = __builtin_nontemporal_load((const f32x4*)(xb + (size_t)e[k] * 128));
#pragma unroll
          for (int k = 0; k < 8; ++k) {
#pragma unroll
            for (int j = 0; j < 4; ++j) {
              float f = v[k][j];
              float fs = val[k] ? f : 0.f;
              s[j] += fs;
              q[j] += f * fs;
              mn[j] = fminf(mn[j], val[k] ? f : INFINITY);
              mx[j] = fmaxf(mx[j], val[k] ? f : -INFINITY);
            }
          }
        }
      }
#pragma unroll
      for (int j = 0; j < 4; ++j) {
        s[j] += __shfl_xor(s[j], 32, 64);
        q[j] += __shfl_xor(q[j], 32, 64);
        mn[j] = fminf(mn[j], __shfl_xor(mn[j], 32, 64));
        mx[j] = fmaxf(mx[j], __shfl_xor(mx[j], 32, 64));
      }
      float cdeg = deg > 0 ? (float)deg : 1.0f;
      float inv = 1.0f / cdeg;
      f32x4 mean, sd;
#pragma unroll
      for (int j = 0; j < 4; ++j) {
        mean[j] = s[j] * inv;
        float var = q[j] * inv - mean[j] * mean[j];
        var = var > 0.f ? var : 0.f;
        sd[j] = sqrtf(var + 1e-5f);
      }
      if (deg == 0) {
#pragma unroll
        for (int j = 0; j < 4; ++j) { mn[j] = 0.f; mx[j] = 0.f; }
      }
      size_t rb = (size_t)wid * 512;
      if (half == 0) {
        *(uint2*)(agg4 + rb + fh)       = pack4(mean);
        *(uint2*)(agg4 + rb + 128 + fh) = pack4(mn);
      } else {
        *(uint2*)(agg4 + rb + 256 + fh) = pack4(mx);
        *(uint2*)(agg4 + rb + 384 + fh) = pack4(sd);
      }
      if (lane == 0) {
        float ld = logf(cdeg + 1.0f);
        amp[wid] = ld / AVG_DEG_LOG;
        att[wid] = AVG_DEG_LOG / ld;
      }
    }
  }
}

// ---------------- fused scaled GEMM: out = C0 + amp*C1 + att*C2 + b ----------------
// A = agg4 bf16 [Nn][512]; B = Wb bf16 [128][1536] (n-major); 3 K-groups of 512.
__global__ __launch_bounds__(256) void gemm_kernel(
    const unsigned short* __restrict__ agg4, const unsigned short* __restrict__ Wb,
    const float* __restrict__ amp, const float* __restrict__ att,
    const float* __restrict__ bias, float* __restrict__ out, int Nn) {
  __shared__ __align__(16) unsigned short As[64][40];        // 64 rows x 32 k (+8 pad)
  __shared__ __align__(16) unsigned short Bs[3][128][40];    // 3 groups x 128 n x 32 k (+8 pad)
  __shared__ float ampS[64], attS[64];
  int t = threadIdx.x;
  int m0 = blockIdx.x * 64;
  if (t < 64) {
    int n = m0 + t; if (n > Nn - 1) n = Nn - 1;
    ampS[t] = amp[n]; attS[t] = att[n];
  }
  int wave = t >> 6, lane = t & 63;
  int arow = lane & 15, quad = lane >> 4;
  f32x4 acc[3][8];
#pragma unroll
  for (int g = 0; g < 3; ++g)
#pragma unroll
    for (int c8 = 0; c8 < 8; ++c8) acc[g][c8] = (f32x4){0.f, 0.f, 0.f, 0.f};

  int ar = t >> 2;             // 0..63 row for A staging
  int akc = (t & 3) * 8;       // k offset for A staging
  int agr = m0 + ar; if (agr > Nn - 1) agr = Nn - 1;
  const unsigned short* aptr = agg4 + (size_t)agr * 512 + akc;

  for (int kk = 0; kk < 512; kk += 32) {
    __syncthreads();
    *(uint4*)&As[ar][akc] = *(const uint4*)(aptr + kk);
#pragma unroll
    for (int j = 0; j < 6; ++j) {
      int idx = t + j * 256;
      int g = idx >> 9;
      int rem = idx & 511;
      int n = rem >> 2;
      int kc = (rem & 3) * 8;
      *(uint4*)&Bs[g][n][kc] = *(const uint4*)(Wb + (size_t)n * 1536 + g * 512 + kk + kc);
    }
    __syncthreads();
    bf16x8 af = *(bf16x8*)&As[wave * 16 + arow][quad * 8];
#pragma unroll
    for (int g = 0; g < 3; ++g) {
#pragma unroll
      for (int c8 = 0; c8 < 8; ++c8) {
        bf16x8 bf = *(bf16x8*)&Bs[g][c8 * 16 + arow][quad * 8];
        acc[g][c8] = __builtin_amdgcn_mfma_f32_16x16x32_bf16(af, bf, acc[g][c8], 0, 0, 0);
      }
    }
  }
  // epilogue: C layout col=lane&15, row=quad*4+r
#pragma unroll
  for (int c8 = 0; c8 < 8; ++c8) {
    int col = c8 * 16 + arow;
    float bv = bias[col];
#pragma unroll
    for (int r = 0; r < 4; ++r) {
      int lrow = wave * 16 + quad * 4 + r;
      int n = m0 + lrow;
      if (n < Nn) {
        float o = acc[0][c8][r] + ampS[lrow] * acc[1][c8][r] + attS[lrow] * acc[2][c8][r] + bv;
        out[(size_t)n * 128 + col] = o;
      }
    }
  }
}

extern "C" void kernel_launch(void* const* d_in, const int* in_sizes, int n_in,
                              void* d_out, int out_size, void* d_ws, size_t ws_size,
                              hipStream_t stream) {
  const float* x     = (const float*)d_in[0];
  const int*   index = (const int*)d_in[1];
  const float* W     = (const float*)d_in[2];
  const float* bias  = (const float*)d_in[3];
  int E  = in_sizes[1];
  int Nn = out_size / 128;
  float* out = (float*)d_out;

  char* ws = (char*)d_ws;
  size_t off = 0;
  int* cnt     = (int*)(ws + off); off += (size_t)Nn * 4;
  int* cursor  = (int*)(ws + off); off += (size_t)Nn * 4;
  int* offsets = (int*)(ws + off); off += (size_t)(Nn + 1) * 4;
  off = (off + 255) & ~(size_t)255;
  int* bsums   = (int*)(ws + off); off += (size_t)2048 * 4;
  int* edge_ids = (int*)(ws + off); off += (size_t)E * 4;
  off = (off + 255) & ~(size_t)255;
  unsigned short* agg4 = (unsigned short*)(ws + off); off += (size_t)Nn * 512 * 2;
  float* amp = (float*)(ws + off); off += (size_t)Nn * 4;
  float* att = (float*)(ws + off); off += (size_t)Nn * 4;
  off = (off + 255) & ~(size_t)255;
  unsigned short* Wb = (unsigned short*)(ws + off); off += (size_t)128 * 1536 * 2;

  // zero cnt + cursor (contiguous at ws start)
  hipMemsetAsync(ws, 0, (size_t)Nn * 8, stream);

  // co-resident grid size (cached; pure query, capture-safe)
  static int G = 0;
  if (G == 0) {
    int mb = 0;
    hipOccupancyMaxActiveBlocksPerMultiprocessor(&mb, prep_agg_kernel, 256, 0);
    if (mb < 1) mb = 1;
    G = mb * 256;
    if (G > 2048) G = 2048;
  }

  void* kp[] = {(void*)&x, (void*)&index, (void*)&W,
                (void*)&E, (void*)&Nn,
                (void*)&cnt, (void*)&cursor, (void*)&offsets, (void*)&bsums,
                (void*)&edge_ids, (void*)&agg4, (void*)&amp, (void*)&att,
                (void*)&Wb};
  hipLaunchCooperativeKernel((const void*)prep_agg_kernel, dim3(G), dim3(256), kp, 0, stream);

  gemm_kernel<<<(Nn + 63) / 64, 256, 0, stream>>>(agg4, Wb, amp, att, bias, out, Nn);
}

// Round 6
// 692.347 us; speedup vs baseline: 1.6675x; 1.6675x over previous
//
#include <hip/hip_runtime.h>
#include <hip/hip_bf16.h>

typedef __attribute__((ext_vector_type(8))) __bf16 bf16x8;
typedef __attribute__((ext_vector_type(4))) float f32x4;

#define AVG_DEG_LOG 2.833213344056216f

__device__ __forceinline__ unsigned short f2bf(float f) {
  union { float f; unsigned int u; } a; a.f = f;
  unsigned int r = a.u + 0x7FFFu + ((a.u >> 16) & 1u);
  return (unsigned short)(r >> 16);
}

__device__ __forceinline__ uint2 pack4(f32x4 a) {
  uint2 u;
  u.x = (unsigned)f2bf(a[0]) | ((unsigned)f2bf(a[1]) << 16);
  u.y = (unsigned)f2bf(a[2]) | ((unsigned)f2bf(a[3]) << 16);
  return u;
}

// ---------------- fused histogram + W fp32->bf16 ----------------
__global__ void hist_wconv_kernel(const int* __restrict__ idx, int* __restrict__ cnt, int E,
                                  int hb, const float* __restrict__ W,
                                  unsigned short* __restrict__ Wb, int n4) {
  int b = blockIdx.x;
  if (b < hb) {
    int i = b * 256 + threadIdx.x;
    if (i < E) atomicAdd(&cnt[idx[i]], 1);
  } else {
    int i = (b - hb) * 256 + threadIdx.x;
    if (i < n4) {
      float4 v = ((const float4*)W)[i];
      ushort4 o;
      o.x = f2bf(v.x); o.y = f2bf(v.y); o.z = f2bf(v.z); o.w = f2bf(v.w);
      ((ushort4*)Wb)[i] = o;
    }
  }
}

// ---------------- 3-phase coalesced exclusive scan ----------------
__global__ __launch_bounds__(256) void scan1_kernel(const int* __restrict__ cnt,
                                                    int* __restrict__ bsums, int N) {
  __shared__ int red[256];
  int t = threadIdx.x;
  int i = blockIdx.x * 256 + t;
  int v = (i < N) ? cnt[i] : 0;
  red[t] = v;
  __syncthreads();
  for (int o = 128; o > 0; o >>= 1) {
    if (t < o) red[t] += red[t + o];
    __syncthreads();
  }
  if (t == 0) bsums[blockIdx.x] = red[0];
}

__global__ __launch_bounds__(256) void scan2_kernel(int* __restrict__ bsums, int nb) {
  __shared__ int sS[256];
  int t = threadIdx.x;
  int v = (t < nb) ? bsums[t] : 0;
  sS[t] = v;
  __syncthreads();
  int val = v;
  for (int o = 1; o < 256; o <<= 1) {
    int add = (t >= o) ? sS[t - o] : 0;
    __syncthreads();
    val += add;
    sS[t] = val;
    __syncthreads();
  }
  if (t < nb) bsums[t] = val - v;  // exclusive
}

__global__ __launch_bounds__(256) void scan3_kernel(const int* __restrict__ cnt,
                                                    const int* __restrict__ bsums,
                                                    int* __restrict__ offsets, int N, int E) {
  __shared__ int sS[256];
  int t = threadIdx.x;
  int i = blockIdx.x * 256 + t;
  int v = (i < N) ? cnt[i] : 0;
  sS[t] = v;
  __syncthreads();
  int val = v;
  for (int o = 1; o < 256; o <<= 1) {
    int add = (t >= o) ? sS[t - o] : 0;
    __syncthreads();
    val += add;
    sS[t] = val;
    __syncthreads();
  }
  if (i < N) offsets[i] = bsums[blockIdx.x] + val - v;
  if (blockIdx.x == 0 && t == 0) offsets[N] = E;  // all edges land in [0,N)
}

// ---------------- scatter edge ids ----------------
__global__ void scatter_kernel(const int* __restrict__ idx, const int* __restrict__ offsets,
                               int* __restrict__ cursor, int* __restrict__ edge_ids, int E) {
  int i = blockIdx.x * blockDim.x + threadIdx.x;
  if (i < E) {
    int n = idx[i];
    int p = atomicAdd(&cursor[n], 1);
    edge_ids[offsets[n] + p] = i;
  }
}

// ---------------- aggregation helpers ----------------
__device__ __forceinline__ void agg_accum_chunk(const float* __restrict__ xb, int eid,
    int ii, int deg, int half, f32x4& s, f32x4& q, f32x4& mn, f32x4& mx) {
  int e[8];
  bool val[8];
#pragma unroll
  for (int k = 0; k < 8; ++k) {
    int p = ii + 2 * k + half;
    val[k] = p < deg;
    int pc = val[k] ? p : deg - 1;
    e[k] = __shfl(eid, pc, 64);
  }
  f32x4 v[8];
#pragma unroll
  for (int k = 0; k < 8; ++k)
    v[k] = __builtin_nontemporal_load((const f32x4*)(xb + (size_t)e[k] * 128));
#pragma unroll
  for (int k = 0; k < 8; ++k) {
#pragma unroll
    for (int j = 0; j < 4; ++j) {
      float f = v[k][j];
      float fs = val[k] ? f : 0.f;
      s[j] += fs;
      q[j] += f * fs;
      mn[j] = fminf(mn[j], val[k] ? f : INFINITY);
      mx[j] = fmaxf(mx[j], val[k] ? f : -INFINITY);
    }
  }
}

// generic (any degree) single-node path — v3 loop
__device__ void agg_one(const float* __restrict__ xb, const int* __restrict__ edge_ids,
    int offs, int deg, int lane, int half, f32x4& s, f32x4& q, f32x4& mn, f32x4& mx) {
  for (int i = 0; i < deg; i += 64) {
    int myid = 0;
    if (i + lane < deg) myid = edge_ids[offs + i + lane];
    int c = deg - i; if (c > 64) c = 64;
    for (int ii = 0; ii < c; ii += 16)
      agg_accum_chunk(xb, myid, ii, c, half, s, q, mn, mx);
  }
}

__device__ void agg_finish(unsigned short* __restrict__ agg4, float* __restrict__ amp,
    float* __restrict__ att, int wid, int deg, int lane, int half, int fh,
    f32x4 s, f32x4 q, f32x4 mn, f32x4 mx) {
#pragma unroll
  for (int j = 0; j < 4; ++j) {
    s[j] += __shfl_xor(s[j], 32, 64);
    q[j] += __shfl_xor(q[j], 32, 64);
    mn[j] = fminf(mn[j], __shfl_xor(mn[j], 32, 64));
    mx[j] = fmaxf(mx[j], __shfl_xor(mx[j], 32, 64));
  }
  float cdeg = deg > 0 ? (float)deg : 1.0f;
  float inv = 1.0f / cdeg;
  f32x4 mean, sd;
#pragma unroll
  for (int j = 0; j < 4; ++j) {
    mean[j] = s[j] * inv;
    float var = q[j] * inv - mean[j] * mean[j];
    var = var > 0.f ? var : 0.f;
    sd[j] = sqrtf(var + 1e-5f);
  }
  if (deg == 0) {
#pragma unroll
    for (int j = 0; j < 4; ++j) { mn[j] = 0.f; mx[j] = 0.f; }
  }
  size_t rb = (size_t)wid * 512;
  if (half == 0) {
    *(uint2*)(agg4 + rb + fh)       = pack4(mean);
    *(uint2*)(agg4 + rb + 128 + fh) = pack4(mn);
  } else {
    *(uint2*)(agg4 + rb + 256 + fh) = pack4(mx);
    *(uint2*)(agg4 + rb + 384 + fh) = pack4(sd);
  }
  if (lane == 0) {
    float ld = logf(cdeg + 1.0f);
    amp[wid] = ld / AVG_DEG_LOG;
    att[wid] = AVG_DEG_LOG / ld;
  }
}

// ---------------- per-node aggregation v4: 2 nodes per wave, interleaved bursts ----------
__global__ __launch_bounds__(256) void agg_kernel(const float* __restrict__ x,
    const int* __restrict__ edge_ids, const int* __restrict__ offsets,
    unsigned short* __restrict__ agg4, float* __restrict__ amp, float* __restrict__ att, int Nn) {
  int gw = blockIdx.x * 4 + (threadIdx.x >> 6);
  int nA = gw * 2, nB = nA + 1;
  if (nA >= Nn) return;
  bool hasB = nB < Nn;
  int lane = threadIdx.x & 63;
  int half = lane >> 5;
  int fh = (lane & 31) * 4;
  const float* xb = x + fh;

  int o0 = offsets[nA];
  int o1 = offsets[nA + 1];
  int o2 = hasB ? offsets[nB + 1] : o1;
  int offsA = o0, degA = o1 - o0;
  int offsB = o1, degB = hasB ? (o2 - o1) : 0;

  f32x4 sA = {0,0,0,0}, qA = {0,0,0,0};
  f32x4 mnA = {INFINITY,INFINITY,INFINITY,INFINITY}, mxA = {-INFINITY,-INFINITY,-INFINITY,-INFINITY};
  f32x4 sB = {0,0,0,0}, qB = {0,0,0,0};
  f32x4 mnB = {INFINITY,INFINITY,INFINITY,INFINITY}, mxB = {-INFINITY,-INFINITY,-INFINITY,-INFINITY};

  if (degA <= 64 && degB <= 64) {
    // fast path: both edge-id vectors up-front, bursts interleaved (16 loads in flight)
    int eidA = 0, eidB = 0;
    if (lane < degA) eidA = edge_ids[offsA + lane];
    if (lane < degB) eidB = edge_ids[offsB + lane];
    int cm = degA > degB ? degA : degB;
    for (int ii = 0; ii < cm; ii += 16) {
      bool doA = ii < degA;
      bool doB = ii < degB;
      int eA[8], eB[8];
      bool valA[8], valB[8];
      f32x4 vA[8], vB[8];
      if (doA) {
#pragma unroll
        for (int k = 0; k < 8; ++k) {
          int p = ii + 2 * k + half;
          valA[k] = p < degA;
          int pc = valA[k] ? p : degA - 1;
          eA[k] = __shfl(eidA, pc, 64);
        }
#pragma unroll
        for (int k = 0; k < 8; ++k)
          vA[k] = __builtin_nontemporal_load((const f32x4*)(xb + (size_t)eA[k] * 128));
      }
      if (doB) {
#pragma unroll
        for (int k = 0; k < 8; ++k) {
          int p = ii + 2 * k + half;
          valB[k] = p < degB;
          int pc = valB[k] ? p : degB - 1;
          eB[k] = __shfl(eidB, pc, 64);
        }
#pragma unroll
        for (int k = 0; k < 8; ++k)
          vB[k] = __builtin_nontemporal_load((const f32x4*)(xb + (size_t)eB[k] * 128));
      }
      if (doA) {
#pragma unroll
        for (int k = 0; k < 8; ++k) {
#pragma unroll
          for (int j = 0; j < 4; ++j) {
            float f = vA[k][j];
            float fs = valA[k] ? f : 0.f;
            sA[j] += fs; qA[j] += f * fs;
            mnA[j] = fminf(mnA[j], valA[k] ? f : INFINITY);
            mxA[j] = fmaxf(mxA[j], valA[k] ? f : -INFINITY);
          }
        }
      }
      if (doB) {
#pragma unroll
        for (int k = 0; k < 8; ++k) {
#pragma unroll
          for (int j = 0; j < 4; ++j) {
            float f = vB[k][j];
            float fs = valB[k] ? f : 0.f;
            sB[j] += fs; qB[j] += f * fs;
            mnB[j] = fminf(mnB[j], valB[k] ? f : INFINITY);
            mxB[j] = fmaxf(mxB[j], valB[k] ? f : -INFINITY);
          }
        }
      }
    }
  } else {
    agg_one(xb, edge_ids, offsA, degA, lane, half, sA, qA, mnA, mxA);
    if (hasB) agg_one(xb, edge_ids, offsB, degB, lane, half, sB, qB, mnB, mxB);
  }

  agg_finish(agg4, amp, att, nA, degA, lane, half, fh, sA, qA, mnA, mxA);
  if (hasB) agg_finish(agg4, amp, att, nB, degB, lane, half, fh, sB, qB, mnB, mxB);
}

// ---------------- fused scaled GEMM: out = C0 + amp*C1 + att*C2 + b ----------------
// A = agg4 bf16 [Nn][512]; B = Wb bf16 [128][1536] (n-major); 3 K-groups of 512.
__global__ __launch_bounds__(256) void gemm_kernel(
    const unsigned short* __restrict__ agg4, const unsigned short* __restrict__ Wb,
    const float* __restrict__ amp, const float* __restrict__ att,
    const float* __restrict__ bias, float* __restrict__ out, int Nn) {
  __shared__ __align__(16) unsigned short As[64][40];        // 64 rows x 32 k (+8 pad)
  __shared__ __align__(16) unsigned short Bs[3][128][40];    // 3 groups x 128 n x 32 k (+8 pad)
  __shared__ float ampS[64], attS[64];
  int t = threadIdx.x;
  int m0 = blockIdx.x * 64;
  if (t < 64) {
    int n = m0 + t; if (n > Nn - 1) n = Nn - 1;
    ampS[t] = amp[n]; attS[t] = att[n];
  }
  int wave = t >> 6, lane = t & 63;
  int arow = lane & 15, quad = lane >> 4;
  f32x4 acc[3][8];
#pragma unroll
  for (int g = 0; g < 3; ++g)
#pragma unroll
    for (int c8 = 0; c8 < 8; ++c8) acc[g][c8] = (f32x4){0.f, 0.f, 0.f, 0.f};

  int ar = t >> 2;             // 0..63 row for A staging
  int akc = (t & 3) * 8;       // k offset for A staging
  int agr = m0 + ar; if (agr > Nn - 1) agr = Nn - 1;
  const unsigned short* aptr = agg4 + (size_t)agr * 512 + akc;

  for (int kk = 0; kk < 512; kk += 32) {
    __syncthreads();
    *(uint4*)&As[ar][akc] = *(const uint4*)(aptr + kk);
#pragma unroll
    for (int j = 0; j < 6; ++j) {
      int idx = t + j * 256;
      int g = idx >> 9;
      int rem = idx & 511;
      int n = rem >> 2;
      int kc = (rem & 3) * 8;
      *(uint4*)&Bs[g][n][kc] = *(const uint4*)(Wb + (size_t)n * 1536 + g * 512 + kk + kc);
    }
    __syncthreads();
    bf16x8 af = *(bf16x8*)&As[wave * 16 + arow][quad * 8];
#pragma unroll
    for (int g = 0; g < 3; ++g) {
#pragma unroll
      for (int c8 = 0; c8 < 8; ++c8) {
        bf16x8 bf = *(bf16x8*)&Bs[g][c8 * 16 + arow][quad * 8];
        acc[g][c8] = __builtin_amdgcn_mfma_f32_16x16x32_bf16(af, bf, acc[g][c8], 0, 0, 0);
      }
    }
  }
  // epilogue: C layout col=lane&15, row=quad*4+r
#pragma unroll
  for (int c8 = 0; c8 < 8; ++c8) {
    int col = c8 * 16 + arow;
    float bv = bias[col];
#pragma unroll
    for (int r = 0; r < 4; ++r) {
      int lrow = wave * 16 + quad * 4 + r;
      int n = m0 + lrow;
      if (n < Nn) {
        float o = acc[0][c8][r] + ampS[lrow] * acc[1][c8][r] + attS[lrow] * acc[2][c8][r] + bv;
        out[(size_t)n * 128 + col] = o;
      }
    }
  }
}

extern "C" void kernel_launch(void* const* d_in, const int* in_sizes, int n_in,
                              void* d_out, int out_size, void* d_ws, size_t ws_size,
                              hipStream_t stream) {
  const float* x     = (const float*)d_in[0];
  const int*   index = (const int*)d_in[1];
  const float* W     = (const float*)d_in[2];
  const float* bias  = (const float*)d_in[3];
  int E  = in_sizes[1];
  int Nn = out_size / 128;
  float* out = (float*)d_out;

  char* ws = (char*)d_ws;
  size_t off = 0;
  int* cnt     = (int*)(ws + off); off += (size_t)Nn * 4;
  int* cursor  = (int*)(ws + off); off += (size_t)Nn * 4;
  int* offsets = (int*)(ws + off); off += (size_t)(Nn + 1) * 4;
  off = (off + 255) & ~(size_t)255;
  int* bsums   = (int*)(ws + off); off += (size_t)256 * 4;
  off = (off + 255) & ~(size_t)255;
  int* edge_ids = (int*)(ws + off); off += (size_t)E * 4;
  off = (off + 255) & ~(size_t)255;
  unsigned short* agg4 = (unsigned short*)(ws + off); off += (size_t)Nn * 512 * 2;
  float* amp = (float*)(ws + off); off += (size_t)Nn * 4;
  float* att = (float*)(ws + off); off += (size_t)Nn * 4;
  off = (off + 255) & ~(size_t)255;
  unsigned short* Wb = (unsigned short*)(ws + off); off += (size_t)128 * 1536 * 2;

  // zero cnt + cursor (contiguous)
  hipMemsetAsync(ws, 0, (size_t)Nn * 8, stream);

  int eb = (E + 255) / 256;
  int n4 = 128 * 1536 / 4;
  int wb = (n4 + 255) / 256;
  int nb = (Nn + 255) / 256;  // 196 scan blocks (<= 256)
  hist_wconv_kernel<<<eb + wb, 256, 0, stream>>>(index, cnt, E, eb, W, Wb, n4);
  scan1_kernel<<<nb, 256, 0, stream>>>(cnt, bsums, Nn);
  scan2_kernel<<<1, 256, 0, stream>>>(bsums, nb);
  scan3_kernel<<<nb, 256, 0, stream>>>(cnt, bsums, offsets, Nn, E);
  scatter_kernel<<<eb, 256, 0, stream>>>(index, offsets, cursor, edge_ids, E);
  agg_kernel<<<(Nn + 7) / 8, 256, 0, stream>>>(x, edge_ids, offsets, agg4, amp, att, Nn);
  gemm_kernel<<<(Nn + 63) / 64, 256, 0, stream>>>(agg4, Wb, amp, att, bias, out, Nn);
}

// Round 7
// 663.027 us; speedup vs baseline: 1.7413x; 1.0442x over previous
//
#include <hip/hip_runtime.h>
#include <hip/hip_bf16.h>

typedef __attribute__((ext_vector_type(8))) __bf16 bf16x8;
typedef __attribute__((ext_vector_type(4))) float f32x4;

#define AVG_DEG_LOG 2.833213344056216f

__device__ __forceinline__ unsigned short f2bf(float f) {
  union { float f; unsigned int u; } a; a.f = f;
  unsigned int r = a.u + 0x7FFFu + ((a.u >> 16) & 1u);
  return (unsigned short)(r >> 16);
}

__device__ __forceinline__ uint2 pack4(f32x4 a) {
  uint2 u;
  u.x = (unsigned)f2bf(a[0]) | ((unsigned)f2bf(a[1]) << 16);
  u.y = (unsigned)f2bf(a[2]) | ((unsigned)f2bf(a[3]) << 16);
  return u;
}

// ---------------- fused histogram (rank-recording) + W fp32->bf16 ----------------
// hist atomicAdd returns the edge's rank within its node -> scatter needs no atomic.
__global__ void hist_wconv_kernel(const int* __restrict__ idx, int* __restrict__ cnt,
                                  int* __restrict__ rank, int E,
                                  int hb, const float* __restrict__ W,
                                  unsigned short* __restrict__ Wb, int n4) {
  int b = blockIdx.x;
  if (b < hb) {
    int i = b * 256 + threadIdx.x;
    if (i < E) rank[i] = atomicAdd(&cnt[idx[i]], 1);
  } else {
    int i = (b - hb) * 256 + threadIdx.x;
    if (i < n4) {
      float4 v = ((const float4*)W)[i];
      ushort4 o;
      o.x = f2bf(v.x); o.y = f2bf(v.y); o.z = f2bf(v.z); o.w = f2bf(v.w);
      ((ushort4*)Wb)[i] = o;
    }
  }
}

// ---------------- 3-phase coalesced exclusive scan ----------------
__global__ __launch_bounds__(256) void scan1_kernel(const int* __restrict__ cnt,
                                                    int* __restrict__ bsums, int N) {
  __shared__ int red[256];
  int t = threadIdx.x;
  int i = blockIdx.x * 256 + t;
  int v = (i < N) ? cnt[i] : 0;
  red[t] = v;
  __syncthreads();
  for (int o = 128; o > 0; o >>= 1) {
    if (t < o) red[t] += red[t + o];
    __syncthreads();
  }
  if (t == 0) bsums[blockIdx.x] = red[0];
}

__global__ __launch_bounds__(256) void scan2_kernel(int* __restrict__ bsums, int nb) {
  __shared__ int sS[256];
  int t = threadIdx.x;
  int v = (t < nb) ? bsums[t] : 0;
  sS[t] = v;
  __syncthreads();
  int val = v;
  for (int o = 1; o < 256; o <<= 1) {
    int add = (t >= o) ? sS[t - o] : 0;
    __syncthreads();
    val += add;
    sS[t] = val;
    __syncthreads();
  }
  if (t < nb) bsums[t] = val - v;  // exclusive
}

__global__ __launch_bounds__(256) void scan3_kernel(const int* __restrict__ cnt,
                                                    const int* __restrict__ bsums,
                                                    int* __restrict__ offsets, int N, int E) {
  __shared__ int sS[256];
  int t = threadIdx.x;
  int i = blockIdx.x * 256 + t;
  int v = (i < N) ? cnt[i] : 0;
  sS[t] = v;
  __syncthreads();
  int val = v;
  for (int o = 1; o < 256; o <<= 1) {
    int add = (t >= o) ? sS[t - o] : 0;
    __syncthreads();
    val += add;
    sS[t] = val;
    __syncthreads();
  }
  if (i < N) offsets[i] = bsums[blockIdx.x] + val - v;
  if (blockIdx.x == 0 && t == 0) offsets[N] = E;  // all edges land in [0,N)
}

// ---------------- scatter edge ids (atomic-free: rank precomputed in hist) ----------------
__global__ void scatter_kernel(const int* __restrict__ idx, const int* __restrict__ offsets,
                               const int* __restrict__ rank, int* __restrict__ edge_ids, int E) {
  int i = blockIdx.x * blockDim.x + threadIdx.x;
  if (i < E) {
    int n = idx[i];
    edge_ids[offsets[n] + rank[i]] = i;
  }
}

// ---------------- aggregation helpers ----------------
__device__ __forceinline__ void agg_accum_chunk(const float* __restrict__ xb, int eid,
    int ii, int deg, int half, f32x4& s, f32x4& q, f32x4& mn, f32x4& mx) {
  int e[8];
  bool val[8];
#pragma unroll
  for (int k = 0; k < 8; ++k) {
    int p = ii + 2 * k + half;
    val[k] = p < deg;
    int pc = val[k] ? p : deg - 1;
    e[k] = __shfl(eid, pc, 64);
  }
  f32x4 v[8];
#pragma unroll
  for (int k = 0; k < 8; ++k)
    v[k] = __builtin_nontemporal_load((const f32x4*)(xb + (size_t)e[k] * 128));
#pragma unroll
  for (int k = 0; k < 8; ++k) {
#pragma unroll
    for (int j = 0; j < 4; ++j) {
      float f = v[k][j];
      float fs = val[k] ? f : 0.f;
      s[j] += fs;
      q[j] += f * fs;
      mn[j] = fminf(mn[j], val[k] ? f : INFINITY);
      mx[j] = fmaxf(mx[j], val[k] ? f : -INFINITY);
    }
  }
}

// generic (any degree) single-node path
__device__ void agg_one(const float* __restrict__ xb, const int* __restrict__ edge_ids,
    int offs, int deg, int lane, int half, f32x4& s, f32x4& q, f32x4& mn, f32x4& mx) {
  for (int i = 0; i < deg; i += 64) {
    int myid = 0;
    if (i + lane < deg) myid = edge_ids[offs + i + lane];
    int c = deg - i; if (c > 64) c = 64;
    for (int ii = 0; ii < c; ii += 16)
      agg_accum_chunk(xb, myid, ii, c, half, s, q, mn, mx);
  }
}

__device__ void agg_finish(unsigned short* __restrict__ agg4, float* __restrict__ amp,
    float* __restrict__ att, int wid, int deg, int lane, int half, int fh,
    f32x4 s, f32x4 q, f32x4 mn, f32x4 mx) {
#pragma unroll
  for (int j = 0; j < 4; ++j) {
    s[j] += __shfl_xor(s[j], 32, 64);
    q[j] += __shfl_xor(q[j], 32, 64);
    mn[j] = fminf(mn[j], __shfl_xor(mn[j], 32, 64));
    mx[j] = fmaxf(mx[j], __shfl_xor(mx[j], 32, 64));
  }
  float cdeg = deg > 0 ? (float)deg : 1.0f;
  float inv = 1.0f / cdeg;
  f32x4 mean, sd;
#pragma unroll
  for (int j = 0; j < 4; ++j) {
    mean[j] = s[j] * inv;
    float var = q[j] * inv - mean[j] * mean[j];
    var = var > 0.f ? var : 0.f;
    sd[j] = sqrtf(var + 1e-5f);
  }
  if (deg == 0) {
#pragma unroll
    for (int j = 0; j < 4; ++j) { mn[j] = 0.f; mx[j] = 0.f; }
  }
  size_t rb = (size_t)wid * 512;
  if (half == 0) {
    *(uint2*)(agg4 + rb + fh)       = pack4(mean);
    *(uint2*)(agg4 + rb + 128 + fh) = pack4(mn);
  } else {
    *(uint2*)(agg4 + rb + 256 + fh) = pack4(mx);
    *(uint2*)(agg4 + rb + 384 + fh) = pack4(sd);
  }
  if (lane == 0) {
    float ld = logf(cdeg + 1.0f);
    amp[wid] = ld / AVG_DEG_LOG;
    att[wid] = AVG_DEG_LOG / ld;
  }
}

// ---------------- per-node aggregation v4: 2 nodes per wave, interleaved bursts ----------
__global__ __launch_bounds__(256) void agg_kernel(const float* __restrict__ x,
    const int* __restrict__ edge_ids, const int* __restrict__ offsets,
    unsigned short* __restrict__ agg4, float* __restrict__ amp, float* __restrict__ att, int Nn) {
  int gw = blockIdx.x * 4 + (threadIdx.x >> 6);
  int nA = gw * 2, nB = nA + 1;
  if (nA >= Nn) return;
  bool hasB = nB < Nn;
  int lane = threadIdx.x & 63;
  int half = lane >> 5;
  int fh = (lane & 31) * 4;
  const float* xb = x + fh;

  int o0 = offsets[nA];
  int o1 = offsets[nA + 1];
  int o2 = hasB ? offsets[nB + 1] : o1;
  int offsA = o0, degA = o1 - o0;
  int offsB = o1, degB = hasB ? (o2 - o1) : 0;

  f32x4 sA = {0,0,0,0}, qA = {0,0,0,0};
  f32x4 mnA = {INFINITY,INFINITY,INFINITY,INFINITY}, mxA = {-INFINITY,-INFINITY,-INFINITY,-INFINITY};
  f32x4 sB = {0,0,0,0}, qB = {0,0,0,0};
  f32x4 mnB = {INFINITY,INFINITY,INFINITY,INFINITY}, mxB = {-INFINITY,-INFINITY,-INFINITY,-INFINITY};

  if (degA <= 64 && degB <= 64) {
    // fast path: both edge-id vectors up-front, bursts interleaved (16 loads in flight)
    int eidA = 0, eidB = 0;
    if (lane < degA) eidA = edge_ids[offsA + lane];
    if (lane < degB) eidB = edge_ids[offsB + lane];
    int cm = degA > degB ? degA : degB;
    for (int ii = 0; ii < cm; ii += 16) {
      bool doA = ii < degA;
      bool doB = ii < degB;
      int eA[8], eB[8];
      bool valA[8], valB[8];
      f32x4 vA[8], vB[8];
      if (doA) {
#pragma unroll
        for (int k = 0; k < 8; ++k) {
          int p = ii + 2 * k + half;
          valA[k] = p < degA;
          int pc = valA[k] ? p : degA - 1;
          eA[k] = __shfl(eidA, pc, 64);
        }
#pragma unroll
        for (int k = 0; k < 8; ++k)
          vA[k] = __builtin_nontemporal_load((const f32x4*)(xb + (size_t)eA[k] * 128));
      }
      if (doB) {
#pragma unroll
        for (int k = 0; k < 8; ++k) {
          int p = ii + 2 * k + half;
          valB[k] = p < degB;
          int pc = valB[k] ? p : degB - 1;
          eB[k] = __shfl(eidB, pc, 64);
        }
#pragma unroll
        for (int k = 0; k < 8; ++k)
          vB[k] = __builtin_nontemporal_load((const f32x4*)(xb + (size_t)eB[k] * 128));
      }
      if (doA) {
#pragma unroll
        for (int k = 0; k < 8; ++k) {
#pragma unroll
          for (int j = 0; j < 4; ++j) {
            float f = vA[k][j];
            float fs = valA[k] ? f : 0.f;
            sA[j] += fs; qA[j] += f * fs;
            mnA[j] = fminf(mnA[j], valA[k] ? f : INFINITY);
            mxA[j] = fmaxf(mxA[j], valA[k] ? f : -INFINITY);
          }
        }
      }
      if (doB) {
#pragma unroll
        for (int k = 0; k < 8; ++k) {
#pragma unroll
          for (int j = 0; j < 4; ++j) {
            float f = vB[k][j];
            float fs = valB[k] ? f : 0.f;
            sB[j] += fs; qB[j] += f * fs;
            mnB[j] = fminf(mnB[j], valB[k] ? f : INFINITY);
            mxB[j] = fmaxf(mxB[j], valB[k] ? f : -INFINITY);
          }
        }
      }
    }
  } else {
    agg_one(xb, edge_ids, offsA, degA, lane, half, sA, qA, mnA, mxA);
    if (hasB) agg_one(xb, edge_ids, offsB, degB, lane, half, sB, qB, mnB, mxB);
  }

  agg_finish(agg4, amp, att, nA, degA, lane, half, fh, sA, qA, mnA, mxA);
  if (hasB) agg_finish(agg4, amp, att, nB, degB, lane, half, fh, sB, qB, mnB, mxB);
}

// ---------------- fused scaled GEMM: out = C0 + amp*C1 + att*C2 + b ----------------
// A = agg4 bf16 [Nn][512]; B = Wb bf16 [128][1536] (n-major); 3 K-groups of 512.
__global__ __launch_bounds__(256) void gemm_kernel(
    const unsigned short* __restrict__ agg4, const unsigned short* __restrict__ Wb,
    const float* __restrict__ amp, const float* __restrict__ att,
    const float* __restrict__ bias, float* __restrict__ out, int Nn) {
  __shared__ __align__(16) unsigned short As[64][40];        // 64 rows x 32 k (+8 pad)
  __shared__ __align__(16) unsigned short Bs[3][128][40];    // 3 groups x 128 n x 32 k (+8 pad)
  __shared__ float ampS[64], attS[64];
  int t = threadIdx.x;
  int m0 = blockIdx.x * 64;
  if (t < 64) {
    int n = m0 + t; if (n > Nn - 1) n = Nn - 1;
    ampS[t] = amp[n]; attS[t] = att[n];
  }
  int wave = t >> 6, lane = t & 63;
  int arow = lane & 15, quad = lane >> 4;
  f32x4 acc[3][8];
#pragma unroll
  for (int g = 0; g < 3; ++g)
#pragma unroll
    for (int c8 = 0; c8 < 8; ++c8) acc[g][c8] = (f32x4){0.f, 0.f, 0.f, 0.f};

  int ar = t >> 2;             // 0..63 row for A staging
  int akc = (t & 3) * 8;       // k offset for A staging
  int agr = m0 + ar; if (agr > Nn - 1) agr = Nn - 1;
  const unsigned short* aptr = agg4 + (size_t)agr * 512 + akc;

  for (int kk = 0; kk < 512; kk += 32) {
    __syncthreads();
    *(uint4*)&As[ar][akc] = *(const uint4*)(aptr + kk);
#pragma unroll
    for (int j = 0; j < 6; ++j) {
      int idx = t + j * 256;
      int g = idx >> 9;
      int rem = idx & 511;
      int n = rem >> 2;
      int kc = (rem & 3) * 8;
      *(uint4*)&Bs[g][n][kc] = *(const uint4*)(Wb + (size_t)n * 1536 + g * 512 + kk + kc);
    }
    __syncthreads();
    bf16x8 af = *(bf16x8*)&As[wave * 16 + arow][quad * 8];
#pragma unroll
    for (int g = 0; g < 3; ++g) {
#pragma unroll
      for (int c8 = 0; c8 < 8; ++c8) {
        bf16x8 bf = *(bf16x8*)&Bs[g][c8 * 16 + arow][quad * 8];
        acc[g][c8] = __builtin_amdgcn_mfma_f32_16x16x32_bf16(af, bf, acc[g][c8], 0, 0, 0);
      }
    }
  }
  // epilogue: C layout col=lane&15, row=quad*4+r
#pragma unroll
  for (int c8 = 0; c8 < 8; ++c8) {
    int col = c8 * 16 + arow;
    float bv = bias[col];
#pragma unroll
    for (int r = 0; r < 4; ++r) {
      int lrow = wave * 16 + quad * 4 + r;
      int n = m0 + lrow;
      if (n < Nn) {
        float o = acc[0][c8][r] + ampS[lrow] * acc[1][c8][r] + attS[lrow] * acc[2][c8][r] + bv;
        out[(size_t)n * 128 + col] = o;
      }
    }
  }
}

extern "C" void kernel_launch(void* const* d_in, const int* in_sizes, int n_in,
                              void* d_out, int out_size, void* d_ws, size_t ws_size,
                              hipStream_t stream) {
  const float* x     = (const float*)d_in[0];
  const int*   index = (const int*)d_in[1];
  const float* W     = (const float*)d_in[2];
  const float* bias  = (const float*)d_in[3];
  int E  = in_sizes[1];
  int Nn = out_size / 128;
  float* out = (float*)d_out;

  char* ws = (char*)d_ws;
  size_t off = 0;
  int* cnt     = (int*)(ws + off); off += (size_t)Nn * 4;
  int* offsets = (int*)(ws + off); off += (size_t)(Nn + 1) * 4;
  off = (off + 255) & ~(size_t)255;
  int* bsums   = (int*)(ws + off); off += (size_t)256 * 4;
  off = (off + 255) & ~(size_t)255;
  int* rank    = (int*)(ws + off); off += (size_t)E * 4;
  int* edge_ids = (int*)(ws + off); off += (size_t)E * 4;
  off = (off + 255) & ~(size_t)255;
  unsigned short* agg4 = (unsigned short*)(ws + off); off += (size_t)Nn * 512 * 2;
  float* amp = (float*)(ws + off); off += (size_t)Nn * 4;
  float* att = (float*)(ws + off); off += (size_t)Nn * 4;
  off = (off + 255) & ~(size_t)255;
  unsigned short* Wb = (unsigned short*)(ws + off); off += (size_t)128 * 1536 * 2;

  // zero cnt only (cursor eliminated)
  hipMemsetAsync(cnt, 0, (size_t)Nn * 4, stream);

  int eb = (E + 255) / 256;
  int n4 = 128 * 1536 / 4;
  int wb = (n4 + 255) / 256;
  int nb = (Nn + 255) / 256;  // scan blocks (<= 256)
  hist_wconv_kernel<<<eb + wb, 256, 0, stream>>>(index, cnt, rank, E, eb, W, Wb, n4);
  scan1_kernel<<<nb, 256, 0, stream>>>(cnt, bsums, Nn);
  scan2_kernel<<<1, 256, 0, stream>>>(bsums, nb);
  scan3_kernel<<<nb, 256, 0, stream>>>(cnt, bsums, offsets, Nn, E);
  scatter_kernel<<<eb, 256, 0, stream>>>(index, offsets, rank, edge_ids, E);
  agg_kernel<<<(Nn + 7) / 8, 256, 0, stream>>>(x, edge_ids, offsets, agg4, amp, att, Nn);
  gemm_kernel<<<(Nn + 63) / 64, 256, 0, stream>>>(agg4, Wb, amp, att, bias, out, Nn);
}